// Round 5
// baseline (431.577 us; speedup 1.0000x reference)
//
#include <hip/hip_runtime.h>
#include <math.h>

#define BB 4
#define C 96
#define LL 4096
#define DIN 192
#define DS 16
#define DT 6
#define DX 38          // DT + 2*DS
#define NCH 128        // chunks along L
#define CL 32          // chunk length (NCH*CL == LL)
#define NCHAIN (BB*DIN*DS)   // 12288
#define NBLK_FUSE 512        // (BB*LL)/32
#define EPSF 1e-5f

__device__ __forceinline__ float silu_f(float x){ return x / (1.0f + expf(-x)); }
__device__ __forceinline__ float softplus_f(float x){ return x > 20.0f ? x : log1pf(expf(x)); }

// ---- x (b,C,L) -> seq (b,L,C) -----------------------------------------
__global__ void k_transpose_in(const float* __restrict__ x, float* __restrict__ seq){
    __shared__ float t[32][33];
    int b = blockIdx.z;
    int l0 = blockIdx.x*32, c0 = blockIdx.y*32;
    int tx = threadIdx.x, ty = threadIdx.y;
    t[ty][tx] = x[((size_t)b*C + c0 + ty)*LL + l0 + tx];
    __syncthreads();
    seq[((size_t)b*LL + l0 + ty)*C + c0 + tx] = t[tx][ty];
}

// ---- x channel means over (h,w) ----------------------------------------
__global__ void k_xmean(const float* __restrict__ x, float* __restrict__ xmean){
    __shared__ float red[256];
    int bc = blockIdx.x;
    const float* p = x + (size_t)bc*LL;
    float s = 0.f;
    for (int i = threadIdx.x; i < LL; i += 256) s += p[i];
    red[threadIdx.x] = s; __syncthreads();
    for (int o = 128; o; o >>= 1){
        if (threadIdx.x < o) red[threadIdx.x] += red[threadIdx.x+o];
        __syncthreads();
    }
    if (threadIdx.x == 0) xmean[bc] = red[0] * (1.f/LL);
}

// ---- transpose mamba-half of fus_w: fus_wt[c*96+o] = fus_w[o*192+c] ----
__global__ void k_prep_fusw(const float* __restrict__ fus_w, float* __restrict__ fus_wt){
    int idx = blockIdx.x*256 + threadIdx.x;
    if (idx < C*C){
        int c = idx / C, o = idx % C;
        fus_wt[idx] = fus_w[(size_t)o*(2*C) + c];
    }
}

// ---- fused LayerNorm + in-proj GEMM: 16 tokens/block -------------------
__global__ __launch_bounds__(256) void k_ln_inproj(const float* __restrict__ seq,
        const float* __restrict__ ln_g, const float* __restrict__ ln_b,
        const float* __restrict__ in_w, float* __restrict__ xz){
    __shared__ float hb[16][C];
    int tid = threadIdx.x;
    int wave = tid >> 6, lane = tid & 63;
    int t0 = blockIdx.x*16;
    int tw = wave*4;
    // LN: each wave normalizes 4 tokens straight into LDS
    #pragma unroll
    for (int tt = 0; tt < 4; tt++){
        int tl = tw + tt;
        const float* row = seq + (size_t)(t0 + tl)*C;
        float v0 = row[lane];
        float v1 = (lane < 32) ? row[64 + lane] : 0.f;
        float sum = v0 + v1;
        for (int off = 32; off; off >>= 1) sum += __shfl_xor(sum, off);
        float mu = sum * (1.f/C);
        float d0 = v0 - mu;
        float d1 = (lane < 32) ? (v1 - mu) : 0.f;
        float sq = d0*d0 + d1*d1;
        for (int off = 32; off; off >>= 1) sq += __shfl_xor(sq, off);
        float rstd = rsqrtf(sq * (1.f/C) + EPSF);
        hb[tl][lane] = d0*rstd*ln_g[lane] + ln_b[lane];
        if (lane < 32) hb[tl][64+lane] = d1*rstd*ln_g[64+lane] + ln_b[64+lane];
    }
    __syncthreads();
    // GEMM: weights streamed once per block, 4 tokens/wave
    float acc[4][6];
    #pragma unroll
    for (int t = 0; t < 4; t++)
        #pragma unroll
        for (int j = 0; j < 6; j++) acc[t][j] = 0.f;
    for (int c = 0; c < C; c++){
        const float* wr = in_w + (size_t)c*(2*DIN);
        float w0 = wr[lane], w1 = wr[lane+64], w2 = wr[lane+128],
              w3 = wr[lane+192], w4 = wr[lane+256], w5 = wr[lane+320];
        #pragma unroll
        for (int t = 0; t < 4; t++){
            float hv = hb[tw + t][c];
            acc[t][0] = fmaf(hv, w0, acc[t][0]);
            acc[t][1] = fmaf(hv, w1, acc[t][1]);
            acc[t][2] = fmaf(hv, w2, acc[t][2]);
            acc[t][3] = fmaf(hv, w3, acc[t][3]);
            acc[t][4] = fmaf(hv, w4, acc[t][4]);
            acc[t][5] = fmaf(hv, w5, acc[t][5]);
        }
    }
    #pragma unroll
    for (int t = 0; t < 4; t++){
        float* o = xz + (size_t)(t0 + tw + t)*(2*DIN);
        #pragma unroll
        for (int j = 0; j < 6; j++) o[lane + 64*j] = acc[t][j];
    }
}

// ---- conv+silu, xproj, delta: 16 tokens/block, LDS-staged xs tile ------
__global__ __launch_bounds__(256) void k_conv_xproj(const float* __restrict__ xz,
        const float* __restrict__ conv_w, const float* __restrict__ conv_b,
        const float* __restrict__ xproj_w, const float* __restrict__ dt_w,
        const float* __restrict__ dt_b,
        float* __restrict__ xc, float* __restrict__ delta,
        float* __restrict__ Bm, float* __restrict__ Cm){
    __shared__ float xsb[19][DIN];   // xs rows l0-3 .. l0+15 (zero-padded)
    __shared__ float xcb[16][DIN];
    __shared__ float dbl[16][DX];
    int tid = threadIdx.x;
    int t0 = blockIdx.x*16;
    int l0 = t0 & (LL - 1);
    // stage xs tile + 3-row halo (coalesced; zero cross-batch rows)
    for (int idx = tid; idx < 19*DIN; idx += 256){
        int r = idx / DIN, d = idx % DIN;
        int l = l0 - 3 + r;
        xsb[r][d] = (l >= 0) ? xz[((size_t)(t0 - 3 + r))*(2*DIN) + d] : 0.f;
    }
    __syncthreads();
    // conv + silu (taps from LDS)
    for (int idx = tid; idx < 16*DIN; idx += 256){
        int tl = idx / DIN, d = idx % DIN;
        const float* cw = conv_w + d*4;
        float a = conv_b[d];
        #pragma unroll
        for (int kk = 0; kk < 4; kk++) a = fmaf(cw[kk], xsb[tl + kk][d], a);
        float s = silu_f(a);
        xcb[tl][d] = s;
        xc[(size_t)(t0 + tl)*DIN + d] = s;
    }
    __syncthreads();
    // xproj: full-lane flat loop over 16x38 outputs, 2 accumulators
    for (int idx = tid; idx < 16*DX; idx += 256){
        int tl = idx / DX, o = idx % DX;
        const float* wo = xproj_w + o;
        float a0 = 0.f, a1 = 0.f;
        for (int c = 0; c < DIN; c += 2){
            a0 = fmaf(xcb[tl][c],   wo[(size_t)c*DX],       a0);
            a1 = fmaf(xcb[tl][c+1], wo[(size_t)(c+1)*DX],   a1);
        }
        float a = a0 + a1;
        dbl[tl][o] = a;
        int tg = t0 + tl;
        if (o >= DT && o < DT+DS)      Bm[(size_t)tg*DS + (o-DT)] = a;
        else if (o >= DT+DS)           Cm[(size_t)tg*DS + (o-DT-DS)] = a;
    }
    __syncthreads();
    // delta = softplus(dt @ dt_w + dt_b)
    for (int idx = tid; idx < 16*DIN; idx += 256){
        int tl = idx / DIN, d = idx % DIN;
        float a = dt_b[d];
        #pragma unroll
        for (int r = 0; r < DT; r++) a = fmaf(dbl[tl][r], dt_w[r*DIN + d], a);
        delta[(size_t)(t0 + tl)*DIN + d] = softplus_f(a);
    }
}

// ---- scan phase A: thread = (b, d, chunk); all 16 states in registers --
__global__ __launch_bounds__(192) void k_scan_A(const float* __restrict__ delta,
        const float* __restrict__ xc, const float* __restrict__ Bm,
        const float* __restrict__ A_log,
        float* __restrict__ Pbuf, float* __restrict__ Sbuf){
    int d  = threadIdx.x;            // 0..191
    int ch = blockIdx.x % NCH;
    int b  = blockIdx.x / NCH;
    const float4* ap = (const float4*)(A_log + (size_t)d*DS);
    float4 a0 = ap[0], a1 = ap[1], a2 = ap[2], a3 = ap[3];
    float Av[DS] = {a0.x,a0.y,a0.z,a0.w, a1.x,a1.y,a1.z,a1.w,
                    a2.x,a2.y,a2.z,a2.w, a3.x,a3.y,a3.z,a3.w};
    float P[DS], hs[DS];
    #pragma unroll
    for (int s = 0; s < DS; s++){ Av[s] = -expf(Av[s]); P[s] = 1.f; hs[s] = 0.f; }
    size_t tbase = (size_t)b*LL + (size_t)ch*CL;
    const float*  dp = delta + tbase*DIN + d;
    const float*  xp = xc    + tbase*DIN + d;
    const float4* bp = (const float4*)(Bm + tbase*DS);
    for (int i = 0; i < CL; i++){
        float dv = dp[(size_t)i*DIN];
        float xv = xp[(size_t)i*DIN];
        float4 b0 = bp[4*i+0], b1 = bp[4*i+1], b2 = bp[4*i+2], b3 = bp[4*i+3];
        float bb[DS] = {b0.x,b0.y,b0.z,b0.w, b1.x,b1.y,b1.z,b1.w,
                        b2.x,b2.y,b2.z,b2.w, b3.x,b3.y,b3.z,b3.w};
        float dxv = dv*xv;
        #pragma unroll
        for (int s = 0; s < DS; s++){
            float dA = expf(dv*Av[s]);
            hs[s] = fmaf(dA, hs[s], bb[s]*dxv);
            P[s] *= dA;
        }
    }
    size_t base = (size_t)ch*NCHAIN + ((size_t)b*DIN + d)*DS;
    float4* Pb = (float4*)(Pbuf + base);
    float4* Sb = (float4*)(Sbuf + base);
    #pragma unroll
    for (int q = 0; q < 4; q++){
        Pb[q] = make_float4(P[4*q], P[4*q+1], P[4*q+2], P[4*q+3]);
        Sb[q] = make_float4(hs[4*q], hs[4*q+1], hs[4*q+2], hs[4*q+3]);
    }
}

// ---- scan phase B: carry scan over chunks; Sbuf <- carry-in ------------
__global__ void k_scan_B(const float* __restrict__ Pbuf, float* __restrict__ Sbuf){
    int chain = blockIdx.x*256 + threadIdx.x;
    float h = 0.f;
    for (int ch = 0; ch < NCH; ch++){
        size_t idx = (size_t)ch*NCHAIN + chain;
        float P = Pbuf[idx];
        float S = Sbuf[idx];
        Sbuf[idx] = h;
        h = fmaf(P, h, S);
    }
}

// ---- scan phase C: replay with carry-in, emit raw y (pre-gating) -------
__global__ __launch_bounds__(192) void k_scan_C(const float* __restrict__ delta,
        const float* __restrict__ xc, const float* __restrict__ Bm,
        const float* __restrict__ Cm,
        const float* __restrict__ A_log, const float* __restrict__ Dp,
        const float* __restrict__ Sbuf, float* __restrict__ yraw){
    int d  = threadIdx.x;
    int ch = blockIdx.x % NCH;
    int b  = blockIdx.x / NCH;
    const float4* ap = (const float4*)(A_log + (size_t)d*DS);
    float4 a0 = ap[0], a1 = ap[1], a2 = ap[2], a3 = ap[3];
    float Av[DS] = {a0.x,a0.y,a0.z,a0.w, a1.x,a1.y,a1.z,a1.w,
                    a2.x,a2.y,a2.z,a2.w, a3.x,a3.y,a3.z,a3.w};
    #pragma unroll
    for (int s = 0; s < DS; s++) Av[s] = -expf(Av[s]);
    float Dv = Dp[d];
    size_t base = (size_t)ch*NCHAIN + ((size_t)b*DIN + d)*DS;
    const float4* Sb = (const float4*)(Sbuf + base);
    float4 h0 = Sb[0], h1 = Sb[1], h2 = Sb[2], h3 = Sb[3];
    float h[DS] = {h0.x,h0.y,h0.z,h0.w, h1.x,h1.y,h1.z,h1.w,
                   h2.x,h2.y,h2.z,h2.w, h3.x,h3.y,h3.z,h3.w};
    size_t tbase = (size_t)b*LL + (size_t)ch*CL;
    const float*  dp = delta + tbase*DIN + d;
    const float*  xp = xc    + tbase*DIN + d;
    const float4* bp = (const float4*)(Bm + tbase*DS);
    const float4* cp = (const float4*)(Cm + tbase*DS);
    float* yp = yraw + tbase*DIN + d;
    for (int i = 0; i < CL; i++){
        float dv = dp[(size_t)i*DIN];
        float xv = xp[(size_t)i*DIN];
        float4 b0 = bp[4*i+0], b1 = bp[4*i+1], b2 = bp[4*i+2], b3 = bp[4*i+3];
        float4 c0 = cp[4*i+0], c1 = cp[4*i+1], c2 = cp[4*i+2], c3 = cp[4*i+3];
        float bb[DS] = {b0.x,b0.y,b0.z,b0.w, b1.x,b1.y,b1.z,b1.w,
                        b2.x,b2.y,b2.z,b2.w, b3.x,b3.y,b3.z,b3.w};
        float cc[DS] = {c0.x,c0.y,c0.z,c0.w, c1.x,c1.y,c1.z,c1.w,
                        c2.x,c2.y,c2.z,c2.w, c3.x,c3.y,c3.z,c3.w};
        float dxv = dv*xv;
        float acc0 = 0.f, acc1 = 0.f;
        #pragma unroll
        for (int s = 0; s < DS; s += 2){
            float dA0 = expf(dv*Av[s]);
            float dA1 = expf(dv*Av[s+1]);
            h[s]   = fmaf(dA0, h[s],   bb[s]*dxv);
            h[s+1] = fmaf(dA1, h[s+1], bb[s+1]*dxv);
            acc0 = fmaf(h[s],   cc[s],   acc0);
            acc1 = fmaf(h[s+1], cc[s+1], acc1);
        }
        yp[(size_t)i*DIN] = acc0 + acc1 + Dv*xv;
    }
}

// ---- out-proj GEMM: 32 tokens/block, silu(z) gating, residual add ------
__global__ __launch_bounds__(256) void k_outproj(const float* __restrict__ yraw,
        const float* __restrict__ xz, const float* __restrict__ out_w,
        float* __restrict__ seq){
    __shared__ float ygb[32][DIN];
    int tid = threadIdx.x;
    int wave = tid >> 6, lane = tid & 63;
    int t0 = blockIdx.x*32;
    for (int idx = tid; idx < 32*DIN; idx += 256){
        int tl = idx / DIN, d = idx % DIN;
        int t = t0 + tl;
        float yv = yraw[(size_t)t*DIN + d];
        float zv = xz[(size_t)t*(2*DIN) + DIN + d];
        ygb[tl][d] = yv * silu_f(zv);
    }
    __syncthreads();
    float a0[8], a1[8];
    #pragma unroll
    for (int t = 0; t < 8; t++){ a0[t] = 0.f; a1[t] = 0.f; }
    int tw = wave*8;
    for (int d = 0; d < DIN; d++){
        const float* wr = out_w + (size_t)d*C;
        float w0 = wr[lane];
        float w1 = (lane < 32) ? wr[64 + lane] : 0.f;
        #pragma unroll
        for (int t = 0; t < 8; t++){
            float yv = ygb[tw + t][d];
            a0[t] = fmaf(yv, w0, a0[t]);
            a1[t] = fmaf(yv, w1, a1[t]);
        }
    }
    #pragma unroll
    for (int t = 0; t < 8; t++){
        size_t tg = (size_t)(t0 + tw + t);
        seq[tg*C + lane] += a0[t];
        if (lane < 32) seq[tg*C + 64 + lane] += a1[t];
    }
}

// ---- global pool MLP + fusion constant ---------------------------------
__global__ void k_gp(const float* __restrict__ xmean, const float* __restrict__ gp_w,
        const float* __restrict__ gp_b, const float* __restrict__ fus_w,
        const float* __restrict__ fus_b, float* __restrict__ gconst){
    __shared__ float gp[BB*C];
    int tid = threadIdx.x;         // 0..383
    int b = tid / C, i = tid % C;
    float a = gp_b[i];
    for (int c = 0; c < C; c++) a = fmaf(xmean[b*C + c], gp_w[i*C + c], a);
    gp[tid] = fmaxf(a, 0.f);
    __syncthreads();
    float g = fus_b[i];
    for (int c = 0; c < C; c++) g = fmaf(fus_w[i*(2*C) + C + c], gp[b*C + c], g);
    gconst[tid] = g;
}

// ---- fusion GEMM (32 tokens/block) + per-block BN partial sums ---------
__global__ __launch_bounds__(256) void k_fuse(const float* __restrict__ seq,
        const float* __restrict__ fus_wt, const float* __restrict__ gconst,
        float* __restrict__ outpre, float* __restrict__ psum, float* __restrict__ psq){
    __shared__ float sb[32][C];
    __shared__ float bs[4][C], bq[4][C];
    int tid = threadIdx.x;
    int wave = tid >> 6, lane = tid & 63;
    int t0 = blockIdx.x*32;
    int b = t0 >> 12;
    for (int idx = tid; idx < 32*C; idx += 256){
        int tl = idx / C, c = idx % C;
        sb[tl][c] = seq[(size_t)(t0 + tl)*C + c];
    }
    __syncthreads();
    float g0 = gconst[b*C + lane];
    float g1 = (lane < 32) ? gconst[b*C + 64 + lane] : 0.f;
    float a0[8], a1[8];
    #pragma unroll
    for (int t = 0; t < 8; t++){ a0[t] = g0; a1[t] = g1; }
    int tw = wave*8;
    for (int c = 0; c < C; c++){
        const float* wr = fus_wt + (size_t)c*C;
        float w0 = wr[lane];
        float w1 = (lane < 32) ? wr[64 + lane] : 0.f;
        #pragma unroll
        for (int t = 0; t < 8; t++){
            float sv = sb[tw + t][c];
            a0[t] = fmaf(sv, w0, a0[t]);
            a1[t] = fmaf(sv, w1, a1[t]);
        }
    }
    float s0 = 0.f, q0 = 0.f, s1 = 0.f, q1 = 0.f;
    #pragma unroll
    for (int t = 0; t < 8; t++){
        size_t tg = (size_t)(t0 + tw + t);
        outpre[tg*C + lane] = a0[t];
        s0 += a0[t]; q0 += a0[t]*a0[t];
        if (lane < 32){
            outpre[tg*C + 64 + lane] = a1[t];
            s1 += a1[t]; q1 += a1[t]*a1[t];
        }
    }
    bs[wave][lane] = s0; bq[wave][lane] = q0;
    if (lane < 32){ bs[wave][64+lane] = s1; bq[wave][64+lane] = q1; }
    __syncthreads();
    if (tid < C){
        float s = 0.f, q = 0.f;
        #pragma unroll
        for (int w = 0; w < 4; w++){ s += bs[w][tid]; q += bq[w][tid]; }
        psum[(size_t)blockIdx.x*C + tid] = s;
        psq [(size_t)blockIdx.x*C + tid] = q;
    }
}

// ---- BN statistics -> per-channel scale/shift --------------------------
__global__ void k_bnstat(const float* __restrict__ psum, const float* __restrict__ psq,
        const float* __restrict__ bn_g, const float* __restrict__ bn_b,
        float* __restrict__ scale, float* __restrict__ shift){
    __shared__ float r1[256], r2[256];
    int o = blockIdx.x;
    float s1 = 0.f, s2 = 0.f;
    for (int i = threadIdx.x; i < NBLK_FUSE; i += 256){
        s1 += psum[(size_t)i*C + o];
        s2 += psq [(size_t)i*C + o];
    }
    r1[threadIdx.x] = s1; r2[threadIdx.x] = s2; __syncthreads();
    for (int off = 128; off; off >>= 1){
        if (threadIdx.x < off){ r1[threadIdx.x] += r1[threadIdx.x+off]; r2[threadIdx.x] += r2[threadIdx.x+off]; }
        __syncthreads();
    }
    if (threadIdx.x == 0){
        float N = (float)(BB*LL);
        float mu = r1[0] / N;
        float var = r2[0] / N - mu*mu;
        float sc = bn_g[o] * rsqrtf(var + EPSF);
        scale[o] = sc;
        shift[o] = bn_b[o] - mu*sc;
    }
}

// ---- transpose back + BN apply + residual ------------------------------
__global__ void k_final(const float* __restrict__ outpre, const float* __restrict__ x,
        const float* __restrict__ scale, const float* __restrict__ shift,
        float* __restrict__ out){
    __shared__ float tle[32][33];
    int b = blockIdx.z;
    int l0 = blockIdx.x*32, o0 = blockIdx.y*32;
    int tx = threadIdx.x, ty = threadIdx.y;
    tle[ty][tx] = outpre[((size_t)b*LL + l0 + ty)*C + o0 + tx];
    __syncthreads();
    int o = o0 + ty;
    size_t idx = ((size_t)b*C + o)*LL + l0 + tx;
    out[idx] = tle[tx][ty]*scale[o] + shift[o] + x[idx];
}

extern "C" void kernel_launch(void* const* d_in, const int* in_sizes, int n_in,
                              void* d_out, int out_size, void* d_ws, size_t ws_size,
                              hipStream_t stream){
    const float* x      = (const float*)d_in[0];
    const float* ln_g   = (const float*)d_in[1];
    const float* ln_b   = (const float*)d_in[2];
    const float* in_w   = (const float*)d_in[3];
    const float* conv_w = (const float*)d_in[4];
    const float* conv_b = (const float*)d_in[5];
    const float* xproj_w= (const float*)d_in[6];
    const float* dt_w   = (const float*)d_in[7];
    const float* dt_b   = (const float*)d_in[8];
    const float* A_log  = (const float*)d_in[9];
    const float* Dp     = (const float*)d_in[10];
    const float* out_w  = (const float*)d_in[11];
    const float* gp_w   = (const float*)d_in[12];
    const float* gp_b   = (const float*)d_in[13];
    const float* fus_w  = (const float*)d_in[14];
    const float* fus_b  = (const float*)d_in[15];
    const float* bn_g   = (const float*)d_in[16];
    const float* bn_b   = (const float*)d_in[17];

    float* ws    = (float*)d_ws;
    float* seq   = ws;                                  // B*L*C
    float* xz    = seq   + (size_t)BB*LL*C;             // B*L*2*DIN
    float* xcb   = xz    + (size_t)BB*LL*2*DIN;         // B*L*DIN
    float* delta = xcb   + (size_t)BB*LL*DIN;           // B*L*DIN (scan_C overwrites with yraw)
    float* Bmb   = delta + (size_t)BB*LL*DIN;           // B*L*DS
    float* Cmb   = Bmb   + (size_t)BB*LL*DS;            // B*L*DS
    float* Pbuf  = Cmb   + (size_t)BB*LL*DS;            // NCH*NCHAIN
    float* Sbuf  = Pbuf  + (size_t)NCH*NCHAIN;          // NCH*NCHAIN
    float* xmean = Sbuf  + (size_t)NCH*NCHAIN;          // B*C
    float* gconst= xmean + BB*C;                        // B*C
    float* scale = gconst+ BB*C;                        // C
    float* shift = scale + C;                           // C
    float* fus_wt= shift + C;                           // C*C transposed fusion weight
    float* yraw  = delta;                               // alias: scan_C writes y over delta
    // aliases into xz region (dead after layer loop)
    float* outpre= xz;                                  // B*L*C
    float* psum  = xz + (size_t)BB*LL*C;                // NBLK_FUSE*C
    float* psq   = psum + (size_t)NBLK_FUSE*C;          // NBLK_FUSE*C

    k_transpose_in<<<dim3(LL/32, C/32, BB), dim3(32,32), 0, stream>>>(x, seq);
    k_xmean<<<BB*C, 256, 0, stream>>>(x, xmean);
    k_prep_fusw<<<(C*C + 255)/256, 256, 0, stream>>>(fus_w, fus_wt);

    for (int layer = 0; layer < 2; layer++){
        const float* lng = ln_g   + (size_t)layer*C;
        const float* lnb = ln_b   + (size_t)layer*C;
        const float* inw = in_w   + (size_t)layer*C*2*DIN;
        const float* cw  = conv_w + (size_t)layer*DIN*4;
        const float* cb  = conv_b + (size_t)layer*DIN;
        const float* xpw = xproj_w+ (size_t)layer*DIN*DX;
        const float* dtw = dt_w   + (size_t)layer*DT*DIN;
        const float* dtb = dt_b   + (size_t)layer*DIN;
        const float* alog= A_log  + (size_t)layer*DIN*DS;
        const float* dpp = Dp     + (size_t)layer*DIN;
        const float* ow  = out_w  + (size_t)layer*DIN*C;

        k_ln_inproj <<<(BB*LL)/16, 256, 0, stream>>>(seq, lng, lnb, inw, xz);
        k_conv_xproj<<<(BB*LL)/16, 256, 0, stream>>>(xz, cw, cb, xpw, dtw, dtb, xcb, delta, Bmb, Cmb);
        k_scan_A<<<BB*NCH, 192, 0, stream>>>(delta, xcb, Bmb, alog, Pbuf, Sbuf);
        k_scan_B<<<NCHAIN/256, 256, 0, stream>>>(Pbuf, Sbuf);
        k_scan_C<<<BB*NCH, 192, 0, stream>>>(delta, xcb, Bmb, Cmb, alog, dpp, Sbuf, yraw);
        k_outproj<<<(BB*LL)/32, 256, 0, stream>>>(yraw, xz, ow, seq);
    }

    k_gp<<<1, BB*C, 0, stream>>>(xmean, gp_w, gp_b, fus_w, fus_b, gconst);
    k_fuse<<<(BB*LL)/32, 256, 0, stream>>>(seq, fus_wt, gconst, outpre, psum, psq);
    k_bnstat<<<C, 256, 0, stream>>>(psum, psq, bn_g, bn_b, scale, shift);
    k_final<<<dim3(LL/32, C/32, BB), dim3(32,32), 0, stream>>>(outpre, x, scale, shift, (float*)d_out);
}

// Round 6
// 415.746 us; speedup vs baseline: 1.0381x; 1.0381x over previous
//
#include <hip/hip_runtime.h>
#include <math.h>

#define BB 4
#define C 96
#define LL 4096
#define DIN 192
#define DS 16
#define DT 6
#define DX 38          // DT + 2*DS
#define NCH 128        // chunks along L
#define CL 32          // chunk length (NCH*CL == LL)
#define NCHAIN (BB*DIN*DS)   // 12288
#define NBLK_FUSE 512        // (BB*LL)/32
#define EPSF 1e-5f

__device__ __forceinline__ float silu_f(float x){ return x / (1.0f + expf(-x)); }
__device__ __forceinline__ float softplus_f(float x){ return x > 20.0f ? x : log1pf(expf(x)); }

// ---- x (b,C,L) -> seq (b,L,C) -----------------------------------------
__global__ void k_transpose_in(const float* __restrict__ x, float* __restrict__ seq){
    __shared__ float t[32][33];
    int b = blockIdx.z;
    int l0 = blockIdx.x*32, c0 = blockIdx.y*32;
    int tx = threadIdx.x, ty = threadIdx.y;
    t[ty][tx] = x[((size_t)b*C + c0 + ty)*LL + l0 + tx];
    __syncthreads();
    seq[((size_t)b*LL + l0 + ty)*C + c0 + tx] = t[tx][ty];
}

// ---- x channel means over (h,w) ----------------------------------------
__global__ void k_xmean(const float* __restrict__ x, float* __restrict__ xmean){
    __shared__ float red[256];
    int bc = blockIdx.x;
    const float* p = x + (size_t)bc*LL;
    float s = 0.f;
    for (int i = threadIdx.x; i < LL; i += 256) s += p[i];
    red[threadIdx.x] = s; __syncthreads();
    for (int o = 128; o; o >>= 1){
        if (threadIdx.x < o) red[threadIdx.x] += red[threadIdx.x+o];
        __syncthreads();
    }
    if (threadIdx.x == 0) xmean[bc] = red[0] * (1.f/LL);
}

// ---- transpose mamba-half of fus_w: fus_wt[c*96+o] = fus_w[o*192+c] ----
__global__ void k_prep_fusw(const float* __restrict__ fus_w, float* __restrict__ fus_wt){
    int idx = blockIdx.x*256 + threadIdx.x;
    if (idx < C*C){
        int c = idx / C, o = idx % C;
        fus_wt[idx] = fus_w[(size_t)o*(2*C) + c];
    }
}

// ---- fused LayerNorm + in-proj GEMM: 32 tokens/block -------------------
__global__ __launch_bounds__(256) void k_ln_inproj(const float* __restrict__ seq,
        const float* __restrict__ ln_g, const float* __restrict__ ln_b,
        const float* __restrict__ in_w, float* __restrict__ xz){
    __shared__ float hb[32][C];
    int tid = threadIdx.x;
    int wave = tid >> 6, lane = tid & 63;
    int t0 = blockIdx.x*32;
    int tw = wave*8;
    // LN: each wave normalizes 8 tokens straight into LDS
    #pragma unroll
    for (int tt = 0; tt < 8; tt++){
        int tl = tw + tt;
        const float* row = seq + (size_t)(t0 + tl)*C;
        float v0 = row[lane];
        float v1 = (lane < 32) ? row[64 + lane] : 0.f;
        float sum = v0 + v1;
        for (int off = 32; off; off >>= 1) sum += __shfl_xor(sum, off);
        float mu = sum * (1.f/C);
        float d0 = v0 - mu;
        float d1 = (lane < 32) ? (v1 - mu) : 0.f;
        float sq = d0*d0 + d1*d1;
        for (int off = 32; off; off >>= 1) sq += __shfl_xor(sq, off);
        float rstd = rsqrtf(sq * (1.f/C) + EPSF);
        hb[tl][lane] = d0*rstd*ln_g[lane] + ln_b[lane];
        if (lane < 32) hb[tl][64+lane] = d1*rstd*ln_g[64+lane] + ln_b[64+lane];
    }
    __syncthreads();
    // GEMM: weights streamed once per block, 8 tokens/wave
    float acc[8][6];
    #pragma unroll
    for (int t = 0; t < 8; t++)
        #pragma unroll
        for (int j = 0; j < 6; j++) acc[t][j] = 0.f;
    for (int c = 0; c < C; c++){
        const float* wr = in_w + (size_t)c*(2*DIN);
        float w0 = wr[lane], w1 = wr[lane+64], w2 = wr[lane+128],
              w3 = wr[lane+192], w4 = wr[lane+256], w5 = wr[lane+320];
        #pragma unroll
        for (int t = 0; t < 8; t++){
            float hv = hb[tw + t][c];
            acc[t][0] = fmaf(hv, w0, acc[t][0]);
            acc[t][1] = fmaf(hv, w1, acc[t][1]);
            acc[t][2] = fmaf(hv, w2, acc[t][2]);
            acc[t][3] = fmaf(hv, w3, acc[t][3]);
            acc[t][4] = fmaf(hv, w4, acc[t][4]);
            acc[t][5] = fmaf(hv, w5, acc[t][5]);
        }
    }
    #pragma unroll
    for (int t = 0; t < 8; t++){
        float* o = xz + (size_t)(t0 + tw + t)*(2*DIN);
        #pragma unroll
        for (int j = 0; j < 6; j++) o[lane + 64*j] = acc[t][j];
    }
}

// ---- conv+silu (column-wise, sliding window), xproj, delta -------------
__global__ __launch_bounds__(256) void k_conv_xproj(const float* __restrict__ xz,
        const float* __restrict__ conv_w, const float* __restrict__ conv_b,
        const float* __restrict__ xproj_w, const float* __restrict__ dt_w,
        const float* __restrict__ dt_b,
        float* __restrict__ xc, float* __restrict__ delta,
        float* __restrict__ Bm, float* __restrict__ Cm){
    __shared__ float xcb[32][DIN+1];   // +1 pad: phase-B reads span 2 rows
    __shared__ float dbl[32][DX];
    int tid = threadIdx.x;
    int t0 = blockIdx.x*32;
    int l0 = t0 & (LL - 1);
    // phase A: conv+silu, one thread per channel, coalesced row loads
    if (tid < DIN){
        int d = tid;
        const float* cw = conv_w + d*4;
        float c0 = cw[0], c1 = cw[1], c2 = cw[2], c3 = cw[3];
        float bias = conv_b[d];
        float x0 = 0.f, x1 = 0.f, x2 = 0.f;
        if (l0 > 0){
            x0 = xz[((size_t)(t0-3))*(2*DIN) + d];
            x1 = xz[((size_t)(t0-2))*(2*DIN) + d];
            x2 = xz[((size_t)(t0-1))*(2*DIN) + d];
        }
        for (int i0 = 0; i0 < 32; i0 += 8){
            float xv[8];
            #pragma unroll
            for (int j = 0; j < 8; j++)
                xv[j] = xz[((size_t)(t0 + i0 + j))*(2*DIN) + d];
            #pragma unroll
            for (int j = 0; j < 8; j++){
                float a = fmaf(c3, xv[j], fmaf(c2, x2, fmaf(c1, x1, fmaf(c0, x0, bias))));
                float s = silu_f(a);
                xcb[i0+j][d] = s;
                xc[((size_t)(t0 + i0 + j))*DIN + d] = s;
                x0 = x1; x1 = x2; x2 = xv[j];
            }
        }
    }
    __syncthreads();
    // phase B: xproj, flat over 32x38 outputs
    for (int idx = tid; idx < 32*DX; idx += 256){
        int tl = idx / DX, o = idx % DX;
        const float* wo = xproj_w + o;
        float a0 = 0.f, a1 = 0.f;
        for (int c = 0; c < DIN; c += 2){
            a0 = fmaf(xcb[tl][c],   wo[(size_t)c*DX],     a0);
            a1 = fmaf(xcb[tl][c+1], wo[(size_t)(c+1)*DX], a1);
        }
        float a = a0 + a1;
        dbl[tl][o] = a;
        int tg = t0 + tl;
        if (o >= DT && o < DT+DS)      Bm[(size_t)tg*DS + (o-DT)] = a;
        else if (o >= DT+DS)           Cm[(size_t)tg*DS + (o-DT-DS)] = a;
    }
    __syncthreads();
    // phase C: delta = softplus(dt @ dt_w + dt_b)
    for (int idx = tid; idx < 32*DIN; idx += 256){
        int tl = idx / DIN, d = idx % DIN;
        float a = dt_b[d];
        #pragma unroll
        for (int r = 0; r < DT; r++) a = fmaf(dbl[tl][r], dt_w[r*DIN + d], a);
        delta[(size_t)(t0 + tl)*DIN + d] = softplus_f(a);
    }
}

// ---- scan phase A: thread = (b, d, chunk); all 16 states in registers --
__global__ __launch_bounds__(192) void k_scan_A(const float* __restrict__ delta,
        const float* __restrict__ xc, const float* __restrict__ Bm,
        const float* __restrict__ A_log,
        float* __restrict__ Pbuf, float* __restrict__ Sbuf){
    int d  = threadIdx.x;            // 0..191
    int ch = blockIdx.x % NCH;
    int b  = blockIdx.x / NCH;
    const float4* ap = (const float4*)(A_log + (size_t)d*DS);
    float4 a0 = ap[0], a1 = ap[1], a2 = ap[2], a3 = ap[3];
    float Av[DS] = {a0.x,a0.y,a0.z,a0.w, a1.x,a1.y,a1.z,a1.w,
                    a2.x,a2.y,a2.z,a2.w, a3.x,a3.y,a3.z,a3.w};
    float P[DS], hs[DS];
    #pragma unroll
    for (int s = 0; s < DS; s++){ Av[s] = -expf(Av[s]); P[s] = 1.f; hs[s] = 0.f; }
    size_t tbase = (size_t)b*LL + (size_t)ch*CL;
    const float*  dp = delta + tbase*DIN + d;
    const float*  xp = xc    + tbase*DIN + d;
    const float4* bp = (const float4*)(Bm + tbase*DS);
    for (int i = 0; i < CL; i++){
        float dv = dp[(size_t)i*DIN];
        float xv = xp[(size_t)i*DIN];
        float4 b0 = bp[4*i+0], b1 = bp[4*i+1], b2 = bp[4*i+2], b3 = bp[4*i+3];
        float bb[DS] = {b0.x,b0.y,b0.z,b0.w, b1.x,b1.y,b1.z,b1.w,
                        b2.x,b2.y,b2.z,b2.w, b3.x,b3.y,b3.z,b3.w};
        float dxv = dv*xv;
        #pragma unroll
        for (int s = 0; s < DS; s++){
            float dA = expf(dv*Av[s]);
            hs[s] = fmaf(dA, hs[s], bb[s]*dxv);
            P[s] *= dA;
        }
    }
    size_t base = (size_t)ch*NCHAIN + ((size_t)b*DIN + d)*DS;
    float4* Pb = (float4*)(Pbuf + base);
    float4* Sb = (float4*)(Sbuf + base);
    #pragma unroll
    for (int q = 0; q < 4; q++){
        Pb[q] = make_float4(P[4*q], P[4*q+1], P[4*q+2], P[4*q+3]);
        Sb[q] = make_float4(hs[4*q], hs[4*q+1], hs[4*q+2], hs[4*q+3]);
    }
}

// ---- scan phase B: carry scan over chunks; Sbuf <- carry-in ------------
__global__ void k_scan_B(const float* __restrict__ Pbuf, float* __restrict__ Sbuf){
    int chain = blockIdx.x*256 + threadIdx.x;
    float h = 0.f;
    for (int ch = 0; ch < NCH; ch++){
        size_t idx = (size_t)ch*NCHAIN + chain;
        float P = Pbuf[idx];
        float S = Sbuf[idx];
        Sbuf[idx] = h;
        h = fmaf(P, h, S);
    }
}

// ---- scan phase C fused with out-proj: replay, gate, GEMM, residual ----
__global__ __launch_bounds__(256) void k_scan_C(const float* __restrict__ delta,
        const float* __restrict__ xc, const float* __restrict__ Bm,
        const float* __restrict__ Cm, const float* __restrict__ xz,
        const float* __restrict__ A_log, const float* __restrict__ Dp,
        const float* __restrict__ Sbuf, const float* __restrict__ out_w,
        float* __restrict__ seq){
    __shared__ float ygb[CL][DIN];
    int tid = threadIdx.x;
    int ch = blockIdx.x % NCH;
    int b  = blockIdx.x / NCH;
    size_t tbase = (size_t)b*LL + (size_t)ch*CL;
    if (tid < DIN){
        int d = tid;
        const float4* ap = (const float4*)(A_log + (size_t)d*DS);
        float4 a0 = ap[0], a1 = ap[1], a2 = ap[2], a3 = ap[3];
        float Av[DS] = {a0.x,a0.y,a0.z,a0.w, a1.x,a1.y,a1.z,a1.w,
                        a2.x,a2.y,a2.z,a2.w, a3.x,a3.y,a3.z,a3.w};
        #pragma unroll
        for (int s = 0; s < DS; s++) Av[s] = -expf(Av[s]);
        float Dv = Dp[d];
        size_t base = (size_t)ch*NCHAIN + ((size_t)b*DIN + d)*DS;
        const float4* Sb = (const float4*)(Sbuf + base);
        float4 h0 = Sb[0], h1 = Sb[1], h2 = Sb[2], h3 = Sb[3];
        float h[DS] = {h0.x,h0.y,h0.z,h0.w, h1.x,h1.y,h1.z,h1.w,
                       h2.x,h2.y,h2.z,h2.w, h3.x,h3.y,h3.z,h3.w};
        const float*  dp = delta + tbase*DIN + d;
        const float*  xp = xc    + tbase*DIN + d;
        const float4* bp = (const float4*)(Bm + tbase*DS);
        const float4* cp = (const float4*)(Cm + tbase*DS);
        for (int i = 0; i < CL; i++){
            float dv = dp[(size_t)i*DIN];
            float xv = xp[(size_t)i*DIN];
            float4 b0 = bp[4*i+0], b1 = bp[4*i+1], b2 = bp[4*i+2], b3 = bp[4*i+3];
            float4 c0 = cp[4*i+0], c1 = cp[4*i+1], c2 = cp[4*i+2], c3 = cp[4*i+3];
            float bb[DS] = {b0.x,b0.y,b0.z,b0.w, b1.x,b1.y,b1.z,b1.w,
                            b2.x,b2.y,b2.z,b2.w, b3.x,b3.y,b3.z,b3.w};
            float cc[DS] = {c0.x,c0.y,c0.z,c0.w, c1.x,c1.y,c1.z,c1.w,
                            c2.x,c2.y,c2.z,c2.w, c3.x,c3.y,c3.z,c3.w};
            float dxv = dv*xv;
            float acc0 = 0.f, acc1 = 0.f;
            #pragma unroll
            for (int s = 0; s < DS; s += 2){
                float dA0 = expf(dv*Av[s]);
                float dA1 = expf(dv*Av[s+1]);
                h[s]   = fmaf(dA0, h[s],   bb[s]*dxv);
                h[s+1] = fmaf(dA1, h[s+1], bb[s+1]*dxv);
                acc0 = fmaf(h[s],   cc[s],   acc0);
                acc1 = fmaf(h[s+1], cc[s+1], acc1);
            }
            float yv = acc0 + acc1 + Dv*xv;
            float zv = xz[(tbase + i)*(2*DIN) + DIN + d];
            ygb[i][d] = yv * silu_f(zv);
        }
    }
    __syncthreads();
    // out-proj GEMM + residual: 8 tokens per wave
    int wave = tid >> 6, lane = tid & 63;
    int tw = wave*8;
    float a0[8], a1[8];
    #pragma unroll
    for (int t = 0; t < 8; t++){ a0[t] = 0.f; a1[t] = 0.f; }
    for (int d = 0; d < DIN; d++){
        const float* wr = out_w + (size_t)d*C;
        float w0 = wr[lane];
        float w1 = (lane < 32) ? wr[64 + lane] : 0.f;
        #pragma unroll
        for (int t = 0; t < 8; t++){
            float yv = ygb[tw + t][d];
            a0[t] = fmaf(yv, w0, a0[t]);
            a1[t] = fmaf(yv, w1, a1[t]);
        }
    }
    #pragma unroll
    for (int t = 0; t < 8; t++){
        size_t tg = tbase + tw + t;
        seq[tg*C + lane] += a0[t];
        if (lane < 32) seq[tg*C + 64 + lane] += a1[t];
    }
}

// ---- global pool MLP + fusion constant ---------------------------------
__global__ void k_gp(const float* __restrict__ xmean, const float* __restrict__ gp_w,
        const float* __restrict__ gp_b, const float* __restrict__ fus_w,
        const float* __restrict__ fus_b, float* __restrict__ gconst){
    __shared__ float gp[BB*C];
    int tid = threadIdx.x;         // 0..383
    int b = tid / C, i = tid % C;
    float a = gp_b[i];
    for (int c = 0; c < C; c++) a = fmaf(xmean[b*C + c], gp_w[i*C + c], a);
    gp[tid] = fmaxf(a, 0.f);
    __syncthreads();
    float g = fus_b[i];
    for (int c = 0; c < C; c++) g = fmaf(fus_w[i*(2*C) + C + c], gp[b*C + c], g);
    gconst[tid] = g;
}

// ---- fusion GEMM (32 tokens/block) + per-block BN partial sums ---------
__global__ __launch_bounds__(256) void k_fuse(const float* __restrict__ seq,
        const float* __restrict__ fus_wt, const float* __restrict__ gconst,
        float* __restrict__ outpre, float* __restrict__ psum, float* __restrict__ psq){
    __shared__ float sb[32][C];
    __shared__ float bs[4][C], bq[4][C];
    int tid = threadIdx.x;
    int wave = tid >> 6, lane = tid & 63;
    int t0 = blockIdx.x*32;
    int b = t0 >> 12;
    for (int idx = tid; idx < 32*C; idx += 256){
        int tl = idx / C, c = idx % C;
        sb[tl][c] = seq[(size_t)(t0 + tl)*C + c];
    }
    __syncthreads();
    float g0 = gconst[b*C + lane];
    float g1 = (lane < 32) ? gconst[b*C + 64 + lane] : 0.f;
    float a0[8], a1[8];
    #pragma unroll
    for (int t = 0; t < 8; t++){ a0[t] = g0; a1[t] = g1; }
    int tw = wave*8;
    for (int c = 0; c < C; c++){
        const float* wr = fus_wt + (size_t)c*C;
        float w0 = wr[lane];
        float w1 = (lane < 32) ? wr[64 + lane] : 0.f;
        #pragma unroll
        for (int t = 0; t < 8; t++){
            float sv = sb[tw + t][c];
            a0[t] = fmaf(sv, w0, a0[t]);
            a1[t] = fmaf(sv, w1, a1[t]);
        }
    }
    float s0 = 0.f, q0 = 0.f, s1 = 0.f, q1 = 0.f;
    #pragma unroll
    for (int t = 0; t < 8; t++){
        size_t tg = (size_t)(t0 + tw + t);
        outpre[tg*C + lane] = a0[t];
        s0 += a0[t]; q0 += a0[t]*a0[t];
        if (lane < 32){
            outpre[tg*C + 64 + lane] = a1[t];
            s1 += a1[t]; q1 += a1[t]*a1[t];
        }
    }
    bs[wave][lane] = s0; bq[wave][lane] = q0;
    if (lane < 32){ bs[wave][64+lane] = s1; bq[wave][64+lane] = q1; }
    __syncthreads();
    if (tid < C){
        float s = 0.f, q = 0.f;
        #pragma unroll
        for (int w = 0; w < 4; w++){ s += bs[w][tid]; q += bq[w][tid]; }
        psum[(size_t)blockIdx.x*C + tid] = s;
        psq [(size_t)blockIdx.x*C + tid] = q;
    }
}

// ---- BN statistics -> per-channel scale/shift --------------------------
__global__ void k_bnstat(const float* __restrict__ psum, const float* __restrict__ psq,
        const float* __restrict__ bn_g, const float* __restrict__ bn_b,
        float* __restrict__ scale, float* __restrict__ shift){
    __shared__ float r1[256], r2[256];
    int o = blockIdx.x;
    float s1 = 0.f, s2 = 0.f;
    for (int i = threadIdx.x; i < NBLK_FUSE; i += 256){
        s1 += psum[(size_t)i*C + o];
        s2 += psq [(size_t)i*C + o];
    }
    r1[threadIdx.x] = s1; r2[threadIdx.x] = s2; __syncthreads();
    for (int off = 128; off; off >>= 1){
        if (threadIdx.x < off){ r1[threadIdx.x] += r1[threadIdx.x+off]; r2[threadIdx.x] += r2[threadIdx.x+off]; }
        __syncthreads();
    }
    if (threadIdx.x == 0){
        float N = (float)(BB*LL);
        float mu = r1[0] / N;
        float var = r2[0] / N - mu*mu;
        float sc = bn_g[o] * rsqrtf(var + EPSF);
        scale[o] = sc;
        shift[o] = bn_b[o] - mu*sc;
    }
}

// ---- transpose back + BN apply + residual ------------------------------
__global__ void k_final(const float* __restrict__ outpre, const float* __restrict__ x,
        const float* __restrict__ scale, const float* __restrict__ shift,
        float* __restrict__ out){
    __shared__ float tle[32][33];
    int b = blockIdx.z;
    int l0 = blockIdx.x*32, o0 = blockIdx.y*32;
    int tx = threadIdx.x, ty = threadIdx.y;
    tle[ty][tx] = outpre[((size_t)b*LL + l0 + ty)*C + o0 + tx];
    __syncthreads();
    int o = o0 + ty;
    size_t idx = ((size_t)b*C + o)*LL + l0 + tx;
    out[idx] = tle[tx][ty]*scale[o] + shift[o] + x[idx];
}

extern "C" void kernel_launch(void* const* d_in, const int* in_sizes, int n_in,
                              void* d_out, int out_size, void* d_ws, size_t ws_size,
                              hipStream_t stream){
    const float* x      = (const float*)d_in[0];
    const float* ln_g   = (const float*)d_in[1];
    const float* ln_b   = (const float*)d_in[2];
    const float* in_w   = (const float*)d_in[3];
    const float* conv_w = (const float*)d_in[4];
    const float* conv_b = (const float*)d_in[5];
    const float* xproj_w= (const float*)d_in[6];
    const float* dt_w   = (const float*)d_in[7];
    const float* dt_b   = (const float*)d_in[8];
    const float* A_log  = (const float*)d_in[9];
    const float* Dp     = (const float*)d_in[10];
    const float* out_w  = (const float*)d_in[11];
    const float* gp_w   = (const float*)d_in[12];
    const float* gp_b   = (const float*)d_in[13];
    const float* fus_w  = (const float*)d_in[14];
    const float* fus_b  = (const float*)d_in[15];
    const float* bn_g   = (const float*)d_in[16];
    const float* bn_b   = (const float*)d_in[17];

    float* ws    = (float*)d_ws;
    float* seq   = ws;                                  // B*L*C
    float* xz    = seq   + (size_t)BB*LL*C;             // B*L*2*DIN
    float* xcb   = xz    + (size_t)BB*LL*2*DIN;         // B*L*DIN
    float* delta = xcb   + (size_t)BB*LL*DIN;           // B*L*DIN
    float* Bmb   = delta + (size_t)BB*LL*DIN;           // B*L*DS
    float* Cmb   = Bmb   + (size_t)BB*LL*DS;            // B*L*DS
    float* Pbuf  = Cmb   + (size_t)BB*LL*DS;            // NCH*NCHAIN
    float* Sbuf  = Pbuf  + (size_t)NCH*NCHAIN;          // NCH*NCHAIN
    float* xmean = Sbuf  + (size_t)NCH*NCHAIN;          // B*C
    float* gconst= xmean + BB*C;                        // B*C
    float* scale = gconst+ BB*C;                        // C
    float* shift = scale + C;                           // C
    float* fus_wt= shift + C;                           // C*C transposed fusion weight
    // aliases into xz region (dead after layer loop)
    float* outpre= xz;                                  // B*L*C
    float* psum  = xz + (size_t)BB*LL*C;                // NBLK_FUSE*C
    float* psq   = psum + (size_t)NBLK_FUSE*C;          // NBLK_FUSE*C

    k_transpose_in<<<dim3(LL/32, C/32, BB), dim3(32,32), 0, stream>>>(x, seq);
    k_xmean<<<BB*C, 256, 0, stream>>>(x, xmean);
    k_prep_fusw<<<(C*C + 255)/256, 256, 0, stream>>>(fus_w, fus_wt);

    for (int layer = 0; layer < 2; layer++){
        const float* lng = ln_g   + (size_t)layer*C;
        const float* lnb = ln_b   + (size_t)layer*C;
        const float* inw = in_w   + (size_t)layer*C*2*DIN;
        const float* cw  = conv_w + (size_t)layer*DIN*4;
        const float* cb  = conv_b + (size_t)layer*DIN;
        const float* xpw = xproj_w+ (size_t)layer*DIN*DX;
        const float* dtw = dt_w   + (size_t)layer*DT*DIN;
        const float* dtb = dt_b   + (size_t)layer*DIN;
        const float* alog= A_log  + (size_t)layer*DIN*DS;
        const float* dpp = Dp     + (size_t)layer*DIN;
        const float* ow  = out_w  + (size_t)layer*DIN*C;

        k_ln_inproj <<<(BB*LL)/32, 256, 0, stream>>>(seq, lng, lnb, inw, xz);
        k_conv_xproj<<<(BB*LL)/32, 256, 0, stream>>>(xz, cw, cb, xpw, dtw, dtb, xcb, delta, Bmb, Cmb);
        k_scan_A<<<BB*NCH, 192, 0, stream>>>(delta, xcb, Bmb, alog, Pbuf, Sbuf);
        k_scan_B<<<NCHAIN/256, 256, 0, stream>>>(Pbuf, Sbuf);
        k_scan_C<<<BB*NCH, 256, 0, stream>>>(delta, xcb, Bmb, Cmb, xz, alog, dpp, Sbuf, ow, seq);
    }

    k_gp<<<1, BB*C, 0, stream>>>(xmean, gp_w, gp_b, fus_w, fus_b, gconst);
    k_fuse<<<(BB*LL)/32, 256, 0, stream>>>(seq, fus_wt, gconst, outpre, psum, psq);
    k_bnstat<<<C, 256, 0, stream>>>(psum, psq, bn_g, bn_b, scale, shift);
    k_final<<<dim3(LL/32, C/32, BB), dim3(32,32), 0, stream>>>(outpre, x, scale, shift, (float*)d_out);
}